// Round 14
// baseline (54.041 us; speedup 1.0000x reference)
//
#include <hip/hip_runtime.h>
#include <stdint.h>

typedef unsigned int u32;
typedef unsigned short u16;
typedef short short8 __attribute__((ext_vector_type(8)));
typedef float f32x16 __attribute__((ext_vector_type(16)));

#define BN 8192
#define NPB 32            // partial tiles per batch (256 rows each)
#define NT 4              // 64-row subtiles per gram block

__device__ __forceinline__ u32 f2b_u(float f){
  u32 x = __float_as_uint(f);
  return (x + 0x7fffu + ((x >> 16) & 1u)) >> 16;   // RNE f32->bf16
}
__device__ __forceinline__ float gelu_exact(float v){
  return 0.5f * v * (1.0f + erff(v * 0.70710678118654752440f));
}
__device__ __forceinline__ void add4(float4& a, const float4 b){
  a.x += b.x; a.y += b.y; a.z += b.z; a.w += b.w;
}

// ---------------------------------------------------------------------------
// K1: per-block partial Gram via MFMA. 256 rows per block (4 subtiles of 64).
// grid = 4*NPB = 128 blocks, 256 threads. (proven r10/r12/r13)
// ---------------------------------------------------------------------------
__global__ __launch_bounds__(256) void k_gram(const float* __restrict__ x,
                                              float* __restrict__ part){
  int bid = blockIdx.x;
  int b = bid >> 5, blk = bid & (NPB - 1);
  int t = threadIdx.x, w = t >> 6, lane = t & 63;
  const float* xb = x + (size_t)b * BN * 64 + (size_t)blk * 256 * 64;

  __shared__ __align__(16) u16 xT[64][72];     // [col][row] bf16, pad 72
  __shared__ float mred[256][16];

  int wi = w >> 1, wj = w & 1;
  int r = t >> 2, cg = t & 3;

  f32x16 acc;
  #pragma unroll
  for (int i = 0; i < 16; ++i) acc[i] = 0.f;
  float macc[16];
  #pragma unroll
  for (int j = 0; j < 16; ++j) macc[j] = 0.f;

  for (int tile = 0; tile < NT; ++tile){
    const float4* src = (const float4*)(xb + ((size_t)(tile * 64 + r)) * 64 + cg * 16);
    float4 v0 = src[0], v1 = src[1], v2 = src[2], v3 = src[3];
    float vv[16] = { v0.x, v0.y, v0.z, v0.w,  v1.x, v1.y, v1.z, v1.w,
                     v2.x, v2.y, v2.z, v2.w,  v3.x, v3.y, v3.z, v3.w };
    #pragma unroll
    for (int j = 0; j < 16; ++j){
      macc[j] += vv[j];
      xT[cg * 16 + j][r] = (u16)f2b_u(vv[j]);
    }
    __syncthreads();

    #pragma unroll
    for (int ks = 0; ks < 4; ++ks){
      int n0 = ks * 16 + (lane >> 5) * 8;
      short8 af = *(const short8*)&xT[wi * 32 + (lane & 31)][n0];
      short8 bf = *(const short8*)&xT[wj * 32 + (lane & 31)][n0];
      acc = __builtin_amdgcn_mfma_f32_32x32x16_bf16(af, bf, acc, 0, 0, 0);
    }
    __syncthreads();
  }

  // C/D map: col = lane&31, row = (reg&3) + 8*(reg>>2) + 4*(lane>>5)
  float* dst = part + (size_t)bid * 4160;
  #pragma unroll
  for (int q = 0; q < 16; ++q){
    int grow = wi * 32 + (q & 3) + 8 * (q >> 2) + 4 * (lane >> 5);
    dst[grow * 64 + wj * 32 + (lane & 31)] = acc[q];
  }

  #pragma unroll
  for (int j = 0; j < 16; ++j) mred[t][j] = macc[j];
  __syncthreads();
  if (t < 64){
    int cgc = t >> 4, j = t & 15;
    float s0 = 0.f, s1 = 0.f, s2 = 0.f, s3 = 0.f;
    for (int ss = 0; ss < 64; ss += 4){
      s0 += mred[cgc + 4 * ss][j];
      s1 += mred[cgc + 4 * (ss + 1)][j];
      s2 += mred[cgc + 4 * (ss + 2)][j];
      s3 += mred[cgc + 4 * (ss + 3)][j];
    }
    dst[4096 + t] = (s0 + s1) + (s2 + s3);
  }
}

// ---------------------------------------------------------------------------
// K2: WIDE reduction of 32 partials -> Gred. grid = 260 blocks, 64 thr.
// (proven r13)
// ---------------------------------------------------------------------------
__global__ __launch_bounds__(64) void k_reduceW(const float4* __restrict__ part4,
                                                float4* __restrict__ Gred4){
  int blk = blockIdx.x;
  int b = blk / 65, chunk = blk - b * 65;
  int t = threadIdx.x;
  int e4 = chunk * 16 + (t & 15);
  int pg = t >> 4;

  __shared__ float4 red[4][16];

  const float4* base = part4 + (size_t)b * NPB * 1040 + e4;
  float4 s = make_float4(0.f, 0.f, 0.f, 0.f);
  #pragma unroll
  for (int p = 0; p < 8; ++p)
    add4(s, base[(size_t)(pg * 8 + p) * 1040]);
  red[pg][t & 15] = s;
  __syncthreads();

  if (t < 16){
    float4 a = red[0][t], c = red[1][t];
    add4(a, red[2][t]);
    add4(c, red[3][t]);
    add4(a, c);
    Gred4[(size_t)b * 1040 + chunk * 16 + t] = a;
  }
}

// ---------------------------------------------------------------------------
// K3: combine (redundant per block) + out. grid = 512 blocks (128/batch),
// 256 threads (4 waves).
//  A: Gred (16.6 KB) -> Gt   B: T = W~k G~   C: St   D: M~ -> LDS bf16
//  E: out = gelu(x~ M~^T) via MFMA for this block's 64 rows.
// LDS overlay: o-struct (18.7 KB) sits inside Gt+Tl (dead after C);
// St at byte 35088+ stays live for D.
// ---------------------------------------------------------------------------
union SM3 {
  struct { float Gt[65*68]; float Tl[64*68]; float St[64*68]; } c;   // 52.5 KB
  struct { u16 Mb16[64][72]; float Mbias[64]; u16 xR[64][72]; } o;   // 18.7 KB
};

__global__ __launch_bounds__(256) void k_outc(
    const float* __restrict__ x, const float4* __restrict__ Gred4,
    const float* __restrict__ Wq, const float* __restrict__ bq,
    const float* __restrict__ Wk, const float* __restrict__ bk,
    const float* __restrict__ Wv, const float* __restrict__ bv,
    const float* __restrict__ Ww, const float* __restrict__ bw,
    float* __restrict__ out)
{
  __shared__ SM3 sm;
  int bid = blockIdx.x;
  int b = bid >> 7, blk = bid & 127;
  int t = threadIdx.x, w = t >> 6, lane = t & 63;
  int rowbase = blk * 64;

  // ---- A: load Gred into Gt ----
  {
    const float4* Gb4 = Gred4 + (size_t)b * 1040;
    for (int g = t; g < 1040; g += 256){
      float4 v = Gb4[g];
      if (g < 1024){
        *(float4*)&sm.c.Gt[(g >> 4) * 68 + (g & 15) * 4] = v;
      } else {
        int j0 = (g - 1024) * 4;
        float mv[4] = { v.x, v.y, v.z, v.w };
        #pragma unroll
        for (int k = 0; k < 4; ++k){
          sm.c.Gt[64 * 68 + j0 + k] = mv[k];
          sm.c.Gt[(j0 + k) * 68 + 64] = mv[k];
        }
      }
    }
    if (t == 0) sm.c.Gt[64 * 68 + 64] = (float)BN;
  }
  __syncthreads();

  // ---- B: T[i][c] = sum_a W~k[i][a] G~[a][c], c = lane; 16 rows/wave ----
  {
    float gcol[65];
    #pragma unroll
    for (int a = 0; a < 65; ++a) gcol[a] = sm.c.Gt[a * 68 + lane];
    for (int i = w * 16; i < w * 16 + 16; ++i){
      float s0 = 0.f, s1 = 0.f, s2 = 0.f, s3 = 0.f;
      #pragma unroll
      for (int a = 0; a < 64; a += 4){
        s0 = fmaf(Wk[i * 64 + a],     gcol[a],     s0);
        s1 = fmaf(Wk[i * 64 + a + 1], gcol[a + 1], s1);
        s2 = fmaf(Wk[i * 64 + a + 2], gcol[a + 2], s2);
        s3 = fmaf(Wk[i * 64 + a + 3], gcol[a + 3], s3);
      }
      sm.c.Tl[i * 68 + lane] = ((s0 + s1) + (s2 + s3)) + bk[i] * gcol[64];
    }
  }
  if (w == 0){   // column 64 of T, lane = i
    float s = 0.f;
    for (int a = 0; a < 64; ++a)
      s = fmaf(Wk[lane * 64 + a], sm.c.Gt[a * 68 + 64], s);
    s = fmaf(bk[lane], (float)BN, s);
    sm.c.Tl[lane * 68 + 64] = s;
  }
  __syncthreads();

  // ---- C: St[j][i] = S[i][j] = sum_c T[i][c] W~v[j][c], j = lane ----
  {
    float wv[65];
    const float4* Wv4 = (const float4*)(Wv + (size_t)lane * 64);
    #pragma unroll
    for (int c4 = 0; c4 < 16; ++c4){
      float4 vv = Wv4[c4];
      wv[4*c4] = vv.x; wv[4*c4+1] = vv.y; wv[4*c4+2] = vv.z; wv[4*c4+3] = vv.w;
    }
    wv[64] = bv[lane];
    for (int i = w * 16; i < w * 16 + 16; ++i){
      const float4* Tr = (const float4*)&sm.c.Tl[i * 68];
      float s0 = 0.f, s1 = 0.f, s2 = 0.f, s3 = 0.f;
      #pragma unroll
      for (int cc = 0; cc < 16; ++cc){
        float4 tv = Tr[cc];
        s0 = fmaf(tv.x, wv[4*cc],     s0);
        s1 = fmaf(tv.y, wv[4*cc + 1], s1);
        s2 = fmaf(tv.z, wv[4*cc + 2], s2);
        s3 = fmaf(tv.w, wv[4*cc + 3], s3);
      }
      sm.c.St[lane * 68 + i] = ((s0 + s1) + (s2 + s3))
                               + sm.c.Tl[i * 68 + 64] * wv[64];
    }
  }
  __syncthreads();

  // ---- D: M~ -> LDS bf16 [64][72] + fp32 bias (overlays Gt; St stays live) --
  {
    const float inv = 1.0f / 65536.0f;   // 1/(sqrt(64)*8192)
    float wq[64];
    #pragma unroll
    for (int i = 0; i < 64; ++i) wq[i] = Wq[i * 64 + lane];   // column c = lane
    for (int d = w * 16; d < w * 16 + 16; ++d){
      const float4* Sr = (const float4*)&sm.c.St[d * 68];
      float s0 = 0.f, s1 = 0.f, s2 = 0.f, s3 = 0.f;
      #pragma unroll
      for (int ii = 0; ii < 16; ++ii){
        float4 sv = Sr[ii];
        s0 = fmaf(sv.x, wq[4*ii],     s0);
        s1 = fmaf(sv.y, wq[4*ii + 1], s1);
        s2 = fmaf(sv.z, wq[4*ii + 2], s2);
        s3 = fmaf(sv.w, wq[4*ii + 3], s3);
      }
      float val = fmaf(inv, (s0 + s1) + (s2 + s3), Ww[d * 64 + lane]);
      sm.o.Mb16[d][lane] = (u16)f2b_u(val);
    }
    if (w == 0){   // affine-const column, lane = d
      float s = 0.f;
      for (int i = 0; i < 64; ++i) s = fmaf(sm.c.St[lane * 68 + i], bq[i], s);
      sm.o.Mbias[lane] = fmaf(inv, s, bw[lane]);
    }
  }
  __syncthreads();

  // ---- E: stage 64 x rows bf16, MFMA, gelu, store ----
  {
    int r = t >> 2, cg = t & 3;
    const float4* src = (const float4*)(x + ((size_t)b * BN + rowbase + r) * 64 + cg * 16);
    float4 v0 = src[0], v1 = src[1], v2 = src[2], v3 = src[3];
    float vv[16] = { v0.x, v0.y, v0.z, v0.w,  v1.x, v1.y, v1.z, v1.w,
                     v2.x, v2.y, v2.z, v2.w,  v3.x, v3.y, v3.z, v3.w };
    #pragma unroll
    for (int j = 0; j < 8; ++j){
      u32 pk = f2b_u(vv[2*j]) | (f2b_u(vv[2*j+1]) << 16);
      *(u32*)&sm.o.xR[r][cg * 16 + 2*j] = pk;
    }
  }
  __syncthreads();

  {
    int wi = w >> 1, wj = w & 1;
    f32x16 oacc;
    #pragma unroll
    for (int i = 0; i < 16; ++i) oacc[i] = 0.f;
    #pragma unroll
    for (int ks = 0; ks < 4; ++ks){
      int c0 = ks * 16 + (lane >> 5) * 8;
      short8 af = *(const short8*)&sm.o.xR  [wi * 32 + (lane & 31)][c0];
      short8 bf = *(const short8*)&sm.o.Mb16[wj * 32 + (lane & 31)][c0];
      oacc = __builtin_amdgcn_mfma_f32_32x32x16_bf16(af, bf, oacc, 0, 0, 0);
    }

    float bias_v = sm.o.Mbias[wj * 32 + (lane & 31)];
    int d = wj * 32 + (lane & 31);
    #pragma unroll
    for (int q = 0; q < 16; ++q){
      int n = rowbase + wi * 32 + (q & 3) + 8 * (q >> 2) + 4 * (lane >> 5);
      out[((size_t)b * BN + n) * 64 + d] = gelu_exact(oacc[q] + bias_v);
    }
  }
}

// ---------------------------------------------------------------------------
extern "C" void kernel_launch(void* const* d_in, const int* in_sizes, int n_in,
                              void* d_out, int out_size, void* d_ws, size_t ws_size,
                              hipStream_t stream) {
  const float* x  = (const float*)d_in[0];
  const float* Wq = (const float*)d_in[1];
  const float* bq = (const float*)d_in[2];
  const float* Wk = (const float*)d_in[3];
  const float* bk = (const float*)d_in[4];
  const float* Wv = (const float*)d_in[5];
  const float* bv = (const float*)d_in[6];
  const float* Ww = (const float*)d_in[7];
  const float* bw = (const float*)d_in[8];
  float* out = (float*)d_out;

  float* ws   = (float*)d_ws;
  float* part = ws;                     // floats [0, 532480)
  float* Gred = ws + 532480;            // 4*4160 = 16640 floats

  k_gram   <<<dim3(4 * NPB), 256, 0, stream>>>(x, part);
  k_reduceW<<<dim3(260),      64, 0, stream>>>((const float4*)part, (float4*)Gred);
  k_outc   <<<dim3(512),     256, 0, stream>>>(x, (const float4*)Gred,
                                               Wq, bq, Wk, bk, Wv, bv, Ww, bw, out);
}

// Round 15
// 22.870 us; speedup vs baseline: 2.3630x; 2.3630x over previous
//
#include <hip/hip_runtime.h>
#include <stdint.h>

typedef unsigned int u32;
typedef unsigned short u16;
typedef short short8 __attribute__((ext_vector_type(8)));
typedef float f32x16 __attribute__((ext_vector_type(16)));

#define BN 8192
#define NPB 32            // partial tiles per batch (256 rows each)
#define NT 4              // 64-row subtiles per gram block

__device__ __forceinline__ u32 f2b_u(float f){
  u32 x = __float_as_uint(f);
  return (x + 0x7fffu + ((x >> 16) & 1u)) >> 16;   // RNE f32->bf16
}
__device__ __forceinline__ float b2f(u16 h){
  return __uint_as_float(((u32)h) << 16);
}
__device__ __forceinline__ float gelu_exact(float v){
  return 0.5f * v * (1.0f + erff(v * 0.70710678118654752440f));
}
__device__ __forceinline__ void add4(float4& a, const float4 b){
  a.x += b.x; a.y += b.y; a.z += b.z; a.w += b.w;
}

// ---------------------------------------------------------------------------
// K1: per-block partial Gram via MFMA. 256 rows per block (4 subtiles of 64).
// grid = 4*NPB = 128 blocks, 256 threads. (proven r10/r12/r13)
// ---------------------------------------------------------------------------
__global__ __launch_bounds__(256) void k_gram(const float* __restrict__ x,
                                              float* __restrict__ part){
  int bid = blockIdx.x;
  int b = bid >> 5, blk = bid & (NPB - 1);
  int t = threadIdx.x, w = t >> 6, lane = t & 63;
  const float* xb = x + (size_t)b * BN * 64 + (size_t)blk * 256 * 64;

  __shared__ __align__(16) u16 xT[64][72];     // [col][row] bf16, pad 72
  __shared__ float mred[256][16];

  int wi = w >> 1, wj = w & 1;
  int r = t >> 2, cg = t & 3;

  f32x16 acc;
  #pragma unroll
  for (int i = 0; i < 16; ++i) acc[i] = 0.f;
  float macc[16];
  #pragma unroll
  for (int j = 0; j < 16; ++j) macc[j] = 0.f;

  for (int tile = 0; tile < NT; ++tile){
    const float4* src = (const float4*)(xb + ((size_t)(tile * 64 + r)) * 64 + cg * 16);
    float4 v0 = src[0], v1 = src[1], v2 = src[2], v3 = src[3];
    float vv[16] = { v0.x, v0.y, v0.z, v0.w,  v1.x, v1.y, v1.z, v1.w,
                     v2.x, v2.y, v2.z, v2.w,  v3.x, v3.y, v3.z, v3.w };
    #pragma unroll
    for (int j = 0; j < 16; ++j){
      macc[j] += vv[j];
      xT[cg * 16 + j][r] = (u16)f2b_u(vv[j]);
    }
    __syncthreads();

    #pragma unroll
    for (int ks = 0; ks < 4; ++ks){
      int n0 = ks * 16 + (lane >> 5) * 8;
      short8 af = *(const short8*)&xT[wi * 32 + (lane & 31)][n0];
      short8 bf = *(const short8*)&xT[wj * 32 + (lane & 31)][n0];
      acc = __builtin_amdgcn_mfma_f32_32x32x16_bf16(af, bf, acc, 0, 0, 0);
    }
    __syncthreads();
  }

  // C/D map: col = lane&31, row = (reg&3) + 8*(reg>>2) + 4*(lane>>5)
  float* dst = part + (size_t)bid * 4160;
  #pragma unroll
  for (int q = 0; q < 16; ++q){
    int grow = wi * 32 + (q & 3) + 8 * (q >> 2) + 4 * (lane >> 5);
    dst[grow * 64 + wj * 32 + (lane & 31)] = acc[q];
  }

  #pragma unroll
  for (int j = 0; j < 16; ++j) mred[t][j] = macc[j];
  __syncthreads();
  if (t < 64){
    int cgc = t >> 4, j = t & 15;
    float s0 = 0.f, s1 = 0.f, s2 = 0.f, s3 = 0.f;
    for (int ss = 0; ss < 64; ss += 4){
      s0 += mred[cgc + 4 * ss][j];
      s1 += mred[cgc + 4 * (ss + 1)][j];
      s2 += mred[cgc + 4 * (ss + 2)][j];
      s3 += mred[cgc + 4 * (ss + 3)][j];
    }
    dst[4096 + t] = (s0 + s1) + (s2 + s3);
  }
}

// ---------------------------------------------------------------------------
// K2: WIDE reduction of 32 partials -> Gred. grid = 260 blocks, 64 thr.
// (proven r13)
// ---------------------------------------------------------------------------
__global__ __launch_bounds__(64) void k_reduceW(const float4* __restrict__ part4,
                                                float4* __restrict__ Gred4){
  int blk = blockIdx.x;
  int b = blk / 65, chunk = blk - b * 65;
  int t = threadIdx.x;
  int e4 = chunk * 16 + (t & 15);
  int pg = t >> 4;

  __shared__ float4 red[4][16];

  const float4* base = part4 + (size_t)b * NPB * 1040 + e4;
  float4 s = make_float4(0.f, 0.f, 0.f, 0.f);
  #pragma unroll
  for (int p = 0; p < 8; ++p)
    add4(s, base[(size_t)(pg * 8 + p) * 1040]);
  red[pg][t & 15] = s;
  __syncthreads();

  if (t < 16){
    float4 a = red[0][t], c = red[1][t];
    add4(a, red[2][t]);
    add4(c, red[3][t]);
    add4(a, c);
    Gred4[(size_t)b * 1040 + chunk * 16 + t] = a;
  }
}

// ---------------------------------------------------------------------------
// K3: per-batch combine via MFMA. grid = 4 blocks, 256 threads (4 waves).
//  stage: G16 (symmetric -> row-major), Wk16, Wv16, WqT16 (transposed),
//         mrow fp32, biases fp32.
//  T = W~k G~ (MFMA + m-border)   S (MFMA + Tcol64-border, stored transposed)
//  M = Ww + inv * St x WqT (MFMA) -> Mws bf16 image + biasws.
// ---------------------------------------------------------------------------
__global__ __launch_bounds__(256) void k_combineM(
    const float* __restrict__ Gred,
    const float* __restrict__ Wq, const float* __restrict__ bq,
    const float* __restrict__ Wk, const float* __restrict__ bk,
    const float* __restrict__ Wv, const float* __restrict__ bv,
    const float* __restrict__ Ww, const float* __restrict__ bw,
    u16* __restrict__ Mws, float* __restrict__ biasws)
{
  int b = blockIdx.x;
  int t = threadIdx.x, w = t >> 6, lane = t & 63;
  int wi = w >> 1, wj = w & 1;
  int r = t >> 2, cg = t & 3;

  __shared__ __align__(16) u16 G16[64][72];
  __shared__ __align__(16) u16 Wk16[64][72];
  __shared__ __align__(16) u16 Wv16[64][72];
  __shared__ __align__(16) u16 WqT16[64][72];
  __shared__ __align__(16) u16 T16[64][72];
  __shared__ __align__(16) u16 St16[64][72];
  __shared__ float mrow[72];
  __shared__ float Tcol64[64];
  __shared__ float bkl[64], bvl[64], bql[64];

  const float* Gb = Gred + (size_t)b * 4160;

  // ---- stage all operands ----
  {
    // G16 row r (G symmetric -> row-major is fine), packed u32 writes
    const float4* s4 = (const float4*)(Gb + r * 64 + cg * 16);
    float4 a0 = s4[0], a1 = s4[1], a2 = s4[2], a3 = s4[3];
    float vv[16] = { a0.x,a0.y,a0.z,a0.w, a1.x,a1.y,a1.z,a1.w,
                     a2.x,a2.y,a2.z,a2.w, a3.x,a3.y,a3.z,a3.w };
    #pragma unroll
    for (int j = 0; j < 8; ++j)
      *(u32*)&G16[r][cg * 16 + 2*j] = f2b_u(vv[2*j]) | (f2b_u(vv[2*j+1]) << 16);
  }
  {
    const float4* s4 = (const float4*)(Wk + r * 64 + cg * 16);
    float4 a0 = s4[0], a1 = s4[1], a2 = s4[2], a3 = s4[3];
    float vv[16] = { a0.x,a0.y,a0.z,a0.w, a1.x,a1.y,a1.z,a1.w,
                     a2.x,a2.y,a2.z,a2.w, a3.x,a3.y,a3.z,a3.w };
    #pragma unroll
    for (int j = 0; j < 8; ++j)
      *(u32*)&Wk16[r][cg * 16 + 2*j] = f2b_u(vv[2*j]) | (f2b_u(vv[2*j+1]) << 16);
  }
  {
    const float4* s4 = (const float4*)(Wv + r * 64 + cg * 16);
    float4 a0 = s4[0], a1 = s4[1], a2 = s4[2], a3 = s4[3];
    float vv[16] = { a0.x,a0.y,a0.z,a0.w, a1.x,a1.y,a1.z,a1.w,
                     a2.x,a2.y,a2.z,a2.w, a3.x,a3.y,a3.z,a3.w };
    #pragma unroll
    for (int j = 0; j < 8; ++j)
      *(u32*)&Wv16[r][cg * 16 + 2*j] = f2b_u(vv[2*j]) | (f2b_u(vv[2*j+1]) << 16);
  }
  {
    // WqT16[c][e] = Wq[e][c]: row e = r, scatter by column
    const float4* s4 = (const float4*)(Wq + r * 64 + cg * 16);
    float4 a0 = s4[0], a1 = s4[1], a2 = s4[2], a3 = s4[3];
    float vv[16] = { a0.x,a0.y,a0.z,a0.w, a1.x,a1.y,a1.z,a1.w,
                     a2.x,a2.y,a2.z,a2.w, a3.x,a3.y,a3.z,a3.w };
    #pragma unroll
    for (int j = 0; j < 16; ++j)
      WqT16[cg * 16 + j][r] = (u16)f2b_u(vv[j]);
  }
  if (t < 64){
    mrow[t] = Gb[4096 + t];
    bkl[t] = bk[t];
    bvl[t] = bv[t];
    bql[t] = bq[t];
  }
  if (t == 0) mrow[64] = (float)BN;
  __syncthreads();

  // ---- T = W~k G~ : af = Wk16 rows, bf = G16 rows (G symmetric) ----
  {
    f32x16 tf;
    #pragma unroll
    for (int i = 0; i < 16; ++i) tf[i] = 0.f;
    #pragma unroll
    for (int ks = 0; ks < 4; ++ks){
      int n0 = ks * 16 + (lane >> 5) * 8;
      short8 af = *(const short8*)&Wk16[wi * 32 + (lane & 31)][n0];
      short8 bf = *(const short8*)&G16 [wj * 32 + (lane & 31)][n0];
      tf = __builtin_amdgcn_mfma_f32_32x32x16_bf16(af, bf, tf, 0, 0, 0);
    }
    int c = wj * 32 + (lane & 31);
    float mc = mrow[c];
    #pragma unroll
    for (int q = 0; q < 16; ++q){
      int i = wi * 32 + (q & 3) + 8 * (q >> 2) + 4 * (lane >> 5);
      T16[i][c] = (u16)f2b_u(tf[q] + bkl[i] * mc);
    }
    if (w == 0){   // T column 64, lane = i
      float s = 0.f;
      for (int a = 0; a < 64; ++a) s = fmaf(b2f(Wk16[lane][a]), mrow[a], s);
      Tcol64[lane] = fmaf(bkl[lane], (float)BN, s);
    }
  }
  __syncthreads();

  // ---- S = T W~v^T : af = T16 rows, bf = Wv16 rows; store transposed ----
  {
    f32x16 sf;
    #pragma unroll
    for (int i = 0; i < 16; ++i) sf[i] = 0.f;
    #pragma unroll
    for (int ks = 0; ks < 4; ++ks){
      int n0 = ks * 16 + (lane >> 5) * 8;
      short8 af = *(const short8*)&T16 [wi * 32 + (lane & 31)][n0];
      short8 bf = *(const short8*)&Wv16[wj * 32 + (lane & 31)][n0];
      sf = __builtin_amdgcn_mfma_f32_32x32x16_bf16(af, bf, sf, 0, 0, 0);
    }
    int j = wj * 32 + (lane & 31);
    float bvj = bvl[j];
    #pragma unroll
    for (int q = 0; q < 16; ++q){
      int i = wi * 32 + (q & 3) + 8 * (q >> 2) + 4 * (lane >> 5);
      St16[j][i] = (u16)f2b_u(sf[q] + Tcol64[i] * bvj);   // St[j][i] = S[i][j]
    }
  }
  __syncthreads();

  // ---- M = Ww + inv * (St x WqT): af = St16 rows, bf = WqT16 rows ----
  {
    const float inv = 1.0f / 65536.0f;   // 1/(sqrt(64)*8192)
    f32x16 mf;
    #pragma unroll
    for (int i = 0; i < 16; ++i) mf[i] = 0.f;
    #pragma unroll
    for (int ks = 0; ks < 4; ++ks){
      int n0 = ks * 16 + (lane >> 5) * 8;
      short8 af = *(const short8*)&St16 [wi * 32 + (lane & 31)][n0];
      short8 bf = *(const short8*)&WqT16[wj * 32 + (lane & 31)][n0];
      mf = __builtin_amdgcn_mfma_f32_32x32x16_bf16(af, bf, mf, 0, 0, 0);
    }
    int c = wj * 32 + (lane & 31);
    u16* Mb = Mws + (size_t)b * 4608;
    #pragma unroll
    for (int q = 0; q < 16; ++q){
      int d = wi * 32 + (q & 3) + 8 * (q >> 2) + 4 * (lane >> 5);
      float val = fmaf(inv, mf[q], Ww[d * 64 + c]);
      Mb[d * 72 + c] = (u16)f2b_u(val);
    }
    if (w == 0){   // bias column, lane = d
      float s = 0.f;
      for (int e = 0; e < 64; ++e) s = fmaf(b2f(St16[lane][e]), bql[e], s);
      biasws[b * 64 + lane] = fmaf(inv, s, bw[lane]);
    }
  }
}

// ---------------------------------------------------------------------------
// K4: out = gelu(x~ M~^T) via MFMA. grid = 512 blocks (128/batch, 64 rows),
// 256 threads (4 waves: wi = row-half, wj = d-half). (proven r12/r13)
// ---------------------------------------------------------------------------
__global__ __launch_bounds__(256) void k_out(const float* __restrict__ x,
                                             const u32* __restrict__ Mws,
                                             const float* __restrict__ biasws,
                                             float* __restrict__ out)
{
  int bid = blockIdx.x;
  int b = bid >> 7, blk = bid & 127;
  int t = threadIdx.x, w = t >> 6, lane = t & 63;
  int rowbase = blk * 64;

  __shared__ __align__(16) u16 Mb16[64][72];
  __shared__ __align__(16) u16 xR[64][72];
  __shared__ float Mbias[64];

  // copy M image (2304 u32) + bias
  {
    const u32* Msrc = Mws + (size_t)b * 2304;
    u32* Mdst = (u32*)&Mb16[0][0];
    #pragma unroll
    for (int i = 0; i < 9; ++i) Mdst[t + 256 * i] = Msrc[t + 256 * i];
    if (t < 64) Mbias[t] = biasws[b * 64 + t];
  }

  // stage 64 x rows, bf16 row-major
  {
    int r = t >> 2, cg = t & 3;
    const float4* src = (const float4*)(x + ((size_t)b * BN + rowbase + r) * 64 + cg * 16);
    float4 v0 = src[0], v1 = src[1], v2 = src[2], v3 = src[3];
    float vv[16] = { v0.x, v0.y, v0.z, v0.w,  v1.x, v1.y, v1.z, v1.w,
                     v2.x, v2.y, v2.z, v2.w,  v3.x, v3.y, v3.z, v3.w };
    #pragma unroll
    for (int j = 0; j < 8; ++j){
      u32 pk = f2b_u(vv[2*j]) | (f2b_u(vv[2*j+1]) << 16);
      *(u32*)&xR[r][cg * 16 + 2*j] = pk;
    }
  }
  __syncthreads();

  int wi = w >> 1, wj = w & 1;
  f32x16 oacc;
  #pragma unroll
  for (int i = 0; i < 16; ++i) oacc[i] = 0.f;
  #pragma unroll
  for (int ks = 0; ks < 4; ++ks){
    int c0 = ks * 16 + (lane >> 5) * 8;
    short8 af = *(const short8*)&xR  [wi * 32 + (lane & 31)][c0];
    short8 bf = *(const short8*)&Mb16[wj * 32 + (lane & 31)][c0];
    oacc = __builtin_amdgcn_mfma_f32_32x32x16_bf16(af, bf, oacc, 0, 0, 0);
  }

  float bias_v = Mbias[wj * 32 + (lane & 31)];
  int d = wj * 32 + (lane & 31);
  #pragma unroll
  for (int q = 0; q < 16; ++q){
    int n = rowbase + wi * 32 + (q & 3) + 8 * (q >> 2) + 4 * (lane >> 5);
    out[((size_t)b * BN + n) * 64 + d] = gelu_exact(oacc[q] + bias_v);
  }
}

// ---------------------------------------------------------------------------
extern "C" void kernel_launch(void* const* d_in, const int* in_sizes, int n_in,
                              void* d_out, int out_size, void* d_ws, size_t ws_size,
                              hipStream_t stream) {
  const float* x  = (const float*)d_in[0];
  const float* Wq = (const float*)d_in[1];
  const float* bq = (const float*)d_in[2];
  const float* Wk = (const float*)d_in[3];
  const float* bk = (const float*)d_in[4];
  const float* Wv = (const float*)d_in[5];
  const float* bv = (const float*)d_in[6];
  const float* Ww = (const float*)d_in[7];
  const float* bw = (const float*)d_in[8];
  float* out = (float*)d_out;

  float* ws     = (float*)d_ws;
  float* part   = ws;                     // floats [0, 532480)
  float* Gred   = ws + 532480;            // 4*4160 = 16640 floats
  u16*   Mws    = (u16*)(ws + 549120);    // 4*4608 u16 = 36864 B = 9216 floats
  float* biasws = ws + 549120 + 9216;     // 256 floats

  k_gram    <<<dim3(4 * NPB), 256, 0, stream>>>(x, part);
  k_reduceW <<<dim3(260),      64, 0, stream>>>((const float4*)part, (float4*)Gred);
  k_combineM<<<dim3(4),       256, 0, stream>>>(Gred, Wq, bq, Wk, bk,
                                                Wv, bv, Ww, bw, Mws, biasws);
  k_out     <<<dim3(512),     256, 0, stream>>>(x, (const u32*)Mws, biasws, out);
}